// Round 9
// baseline (11548.415 us; speedup 1.0000x reference)
//
#include <hip/hip_runtime.h>
#include <math.h>

#define B_ 2
#define N_ 8192          // points per batch
#define G_ 64
#define NG 4096          // G*G latent grid points
#define WID_ 64
#define K_ 16
#define CIN_ 6
#define COUT_ 3
#define PI_ 3.14159265358979323846

typedef unsigned long long u64k;

// ---------------------------------------------------------------- helpers
__device__ __forceinline__ float gelu_f(float x) {
    return 0.5f * x * (1.0f + erff(x * 0.70710678118654752440f));
}
__device__ __forceinline__ int cellof(float v) {
    int c = (int)floorf((v + 1.0f) * 32.0f);
    return min(63, max(0, c));
}
__device__ __forceinline__ u64k umin64(u64k a, u64k b) { return a < b ? a : b; }
__device__ __forceinline__ u64k umax64(u64k a, u64k b) { return a < b ? b : a; }
__device__ __forceinline__ u64k shflxor64(u64k v, int m) {
    return (u64k)__shfl_xor((long long)v, m, 64);
}
__device__ __forceinline__ void bsort64(u64k& key, int lane) {
#pragma unroll
    for (int sz = 2; sz <= 64; sz <<= 1) {
#pragma unroll
        for (int j = sz >> 1; j >= 1; j >>= 1) {
            u64k o = shflxor64(key, j);
            bool keep_min = ((lane & j) == 0) == ((lane & sz) == 0);
            key = keep_min ? umin64(key, o) : umax64(key, o);
        }
    }
}
__device__ __forceinline__ void bmerge_into(u64k& R, u64k key, int lane) {
    u64k o = shflxor64(key, 63);
    u64k L = umin64(R, o);
#pragma unroll
    for (int j = 32; j >= 1; j >>= 1) {
        u64k t = shflxor64(L, j);
        L = ((lane & j) == 0) ? umin64(L, t) : umax64(L, t);
    }
    R = L;
}

// ---------------------------------------------------------------- binning (+ grid gen fused)
__global__ void k_bincount(const float2* __restrict__ coords, int* __restrict__ cnt,
                           float4* __restrict__ gp) {
    int t = blockIdx.x * blockDim.x + threadIdx.x;
    if (t < NG) {        // numpy linspace semantics grid gen
        int i = t >> 6, j = t & 63;
        double st = 2.0 / 63.0;
        float gx = (i == 63) ? 1.0f : (float)(-1.0 + st * (double)i);
        float gy = (j == 63) ? 1.0f : (float)(-1.0 + st * (double)j);
        float s2 = __fadd_rn(__fmul_rn(gx, gx), __fmul_rn(gy, gy));
        gp[t] = make_float4(gx, gy, s2, 0.f);
    }
    if (t >= B_ * N_) return;
    float2 c = coords[t];
    int b = t >> 13;
    int cell = cellof(c.x) * 64 + cellof(c.y);
    atomicAdd(&cnt[b * 4096 + cell], 1);
}
__global__ void k_binscan(const int* __restrict__ cnt, int* __restrict__ offs) {
    int b = blockIdx.x, t = threadIdx.x;    // 1024 threads
    __shared__ int s[1024];
    int4 v = ((const int4*)(cnt + b * 4096))[t];
    int sum = v.x + v.y + v.z + v.w;
    s[t] = sum;
    __syncthreads();
    for (int d = 1; d < 1024; d <<= 1) {
        int x = (t >= d) ? s[t - d] : 0;
        __syncthreads();
        s[t] += x;
        __syncthreads();
    }
    int incl = s[t], excl = incl - sum;
    int* ob = offs + b * 4097;
    ob[4 * t] = excl; ob[4 * t + 1] = excl + v.x;
    ob[4 * t + 2] = excl + v.x + v.y; ob[4 * t + 3] = excl + v.x + v.y + v.z;
    if (t == 1023) ob[4096] = incl;
}
__global__ void k_binscatter(const float2* __restrict__ coords, const int* __restrict__ offs,
                             int* __restrict__ fill, float4* __restrict__ srt) {
    int t = blockIdx.x * blockDim.x + threadIdx.x;
    if (t >= B_ * N_) return;
    float2 c = coords[t];
    int b = t >> 13, n = t & 8191;
    int cell = cellof(c.x) * 64 + cellof(c.y);
    int pos = offs[b * 4097 + cell] + atomicAdd(&fill[b * 4096 + cell], 1);
    float s2 = __fadd_rn(__fmul_rn(c.x, c.x), __fmul_rn(c.y, c.y));
    srt[b * N_ + pos] = make_float4(c.x, c.y, s2, __int_as_float(n));
}

// ---------------------------------------------------------------- pad W1 (71x64) into 72 rows, row 7 = 0
__global__ void k_padw1(const float* __restrict__ w1a, const float* __restrict__ w1b,
                        float* __restrict__ pa, float* __restrict__ pb) {
    int t = blockIdx.x * 256 + threadIdx.x;     // < 2*4608
    if (t >= 2 * 4608) return;
    int which = t / 4608, idx = t - which * 4608;
    int row = idx >> 6, col = idx & 63;
    const float* src = which ? w1b : w1a;
    float v = (row == 7) ? 0.f : src[(row - (row > 6)) * 64 + col];
    (which ? pb : pa)[idx] = v;
}

// ---------------------------------------------------------------- lift MLP
__global__ void __launch_bounds__(256) k_lift(
    const float* __restrict__ fin, const float* __restrict__ W1,
    const float* __restrict__ b1, const float* __restrict__ W2,
    const float* __restrict__ b2, float* __restrict__ fout) {
    __shared__ float xr[4][8];
    __shared__ __align__(16) float h[4][64];
    int ql = threadIdx.x >> 6, j = threadIdx.x & 63;
    int node = blockIdx.x * 4 + ql;
    if (j < CIN_) xr[ql][j] = fin[node * CIN_ + j];
    __syncthreads();
    float a = b1[j];
#pragma unroll
    for (int i = 0; i < CIN_; i++) a = fmaf(xr[ql][i], W1[i * 64 + j], a);
    h[ql][j] = gelu_f(a);
    __syncthreads();
    float a2 = b2[j];
    for (int k = 0; k < 64; k += 4) {
        float w0 = W2[(k + 0) * 64 + j], w1 = W2[(k + 1) * 64 + j];
        float w2 = W2[(k + 2) * 64 + j], w3 = W2[(k + 3) * 64 + j];
        const float4 hv = *(const float4*)&h[ql][k];
        a2 = fmaf(hv.x, w0, fmaf(hv.y, w1, fmaf(hv.z, w2, fmaf(hv.w, w3, a2))));
    }
    fout[node * 64 + j] = a2;
}

// ---------------------------------------------------------------- kNN grid->points: one wave per query
__global__ void __launch_bounds__(256) k_knn_in(
    const float4* __restrict__ gp, const float4* __restrict__ srt,
    const int* __restrict__ offs, int* __restrict__ oidx,
    float* __restrict__ odist, float* __restrict__ lastd) {
    int lane = threadIdx.x & 63;
    int w = (blockIdx.x * blockDim.x + threadIdx.x) >> 6;
    int b = w >> 12, p = w & 4095;
    float4 q = gp[p];
    float qx = q.x, qy = q.y, q2 = q.z;
    int cqx = cellof(qx), cqy = cellof(qy);
    const float4* S = srt + b * N_;
    const int* OF = offs + b * 4097;

    u64k R = ~0ull;
    u64k pend = ~0ull;
    int fill = 0;

    auto flush = [&]() {
        bsort64(pend, lane);
        bmerge_into(R, pend, lane);
        pend = ~0ull;
        fill = 0;
    };
    auto feed = [&](int s0, int s1) {
        int cnt = s1 - s0;
        while (cnt > 0) {
            int take = min(cnt, 64 - fill);
            int t = lane - fill;
            if (t >= 0 && t < take) {
                float4 sp = S[s0 + t];
                float dot = __fadd_rn(__fmul_rn(qx, sp.x), __fmul_rn(qy, sp.y));
                float d2 = __fsub_rn(__fadd_rn(q2, sp.z), 2.0f * dot);
                d2 = fmaxf(d2, 0.0f);
                pend = ((u64k)__float_as_uint(d2) << 32) | (unsigned)__float_as_int(sp.w);
            }
            fill += take; s0 += take; cnt -= take;
            if (fill == 64) flush();
        }
    };

    {
        int xa = max(cqx - 2, 0), xb = min(cqx + 2, 63);
        int ya = max(cqy - 2, 0), yb = min(cqy + 2, 63);
        for (int cx = xa; cx <= xb; cx++) feed(OF[cx * 64 + ya], OF[cx * 64 + yb + 1]);
    }
    int r = 2;
    while (true) {
        if (fill) flush();
        u64k T = (u64k)__shfl((long long)R, 15, 64);
        float d16 = __uint_as_float((unsigned)(T >> 32));
        float bm = (float)r * 0.03125f;
        if (d16 < bm * bm - 1e-5f) break;
        if (cqx - r <= 0 && cqx + r >= 63 && cqy - r <= 0 && cqy + r >= 63) break;
        r++;
        int ya = max(cqy - r, 0), yb = min(cqy + r, 63);
        if (cqx - r >= 0)  { int c0 = (cqx - r) * 64; feed(OF[c0 + ya], OF[c0 + yb + 1]); }
        if (cqx + r <= 63) { int c0 = (cqx + r) * 64; feed(OF[c0 + ya], OF[c0 + yb + 1]); }
        int xa2 = max(cqx - r + 1, 0), xb2 = min(cqx + r - 1, 63);
        for (int cx = xa2; cx <= xb2; cx++) {
            if (cqy - r >= 0)  { int cc = cx * 64 + cqy - r; feed(OF[cc], OF[cc + 1]); }
            if (cqy + r <= 63) { int cc = cx * 64 + cqy + r; feed(OF[cc], OF[cc + 1]); }
        }
    }
    if (lane < 16) {
        float d2 = __uint_as_float((unsigned)(R >> 32));
        float d = sqrtf(d2);
        oidx[w * 16 + lane] = (int)(unsigned)(R & 0xffffffffu);
        odist[w * 16 + lane] = d;
        if (lane == 15) lastd[w] = d;
    }
}

// ---------------------------------------------------------------- kNN points->grid: one wave per query
__global__ void __launch_bounds__(256) k_knn_out(
    const float2* __restrict__ coords, const float4* __restrict__ gp,
    int* __restrict__ oidx, float* __restrict__ odist, float* __restrict__ lastd) {
    int lane = threadIdx.x & 63;
    int w = (blockIdx.x * blockDim.x + threadIdx.x) >> 6;
    float2 c = coords[w];
    float qx = c.x, qy = c.y;
    float q2 = __fadd_rn(__fmul_rn(qx, qx), __fmul_rn(qy, qy));
    int i0 = (int)floorf((qx + 1.0f) * 31.5f);
    int j0 = (int)floorf((qy + 1.0f) * 31.5f);
    int li = min(max(i0 - 3, 0), 56);
    int lj = min(max(j0 - 3, 0), 56);
    int p = (li + (lane >> 3)) * 64 + (lj + (lane & 7));
    float4 sp = gp[p];
    float dot = __fadd_rn(__fmul_rn(qx, sp.x), __fmul_rn(qy, sp.y));
    float d2 = fmaxf(__fsub_rn(__fadd_rn(q2, sp.z), 2.0f * dot), 0.0f);
    u64k key = ((u64k)__float_as_uint(d2) << 32) | (unsigned)p;
    bsort64(key, lane);
    if (lane < 16) {
        float dd = sqrtf(__uint_as_float((unsigned)(key >> 32)));
        oidx[w * 16 + lane] = (int)(unsigned)(key & 0xffffffffu);
        odist[w * 16 + lane] = dd;
        if (lane == 15) lastd[w] = dd;
    }
}

// ---------------------------------------------------------------- exact lower-median via 32-step bisection
__global__ void __launch_bounds__(1024) k_median_bis(
    const float* __restrict__ vals, int n, float* __restrict__ sig) {
    __shared__ int wred[2][16];
    int tid = threadIdx.x;
    int lane = tid & 63, wv = tid >> 6;
    int cnt_per = n >> 10;           // 8 or 16
    unsigned v[16];
    for (int i = 0; i < cnt_per; i++) v[i] = __float_as_uint(vals[tid + (i << 10)]);
    int r = (n - 1) >> 1;
    unsigned prefix = 0;
    for (int bit = 31; bit >= 0; bit--) {
        unsigned cand = prefix | (1u << bit);
        int c = 0;
        for (int i = 0; i < cnt_per; i++) c += (v[i] < cand) ? 1 : 0;
        for (int o = 32; o >= 1; o >>= 1) c += __shfl_down(c, o, 64);
        int buf = bit & 1;
        if (lane == 0) wred[buf][wv] = c;
        __syncthreads();
        int tot = 0;
#pragma unroll
        for (int k = 0; k < 16; k++) tot += wred[buf][k];
        prefix = (tot <= r) ? cand : prefix;
    }
    if (tid == 0) *sig = fmaxf(__uint_as_float(prefix), 1e-6f);
}

// ---------------------------------------------------------------- edge MLP + weighted aggregation (v6)
// One block (4 waves) per 8 queries; wave wv owns edge slice wv*4..+3.
// Double-buffered weight loads use 16 INDIVIDUALLY NAMED float4 registers via
// macros (no arrays / pointers / lambdas) so nothing can be demoted to
// scratch (v5's 1.4 GB spill bug). Layer 1 uses the 72-row padded W1 copy.
#define LOADA(Wp, c) { const float* _w = (Wp) + (c) * 256 + j0; \
    wa0 = *(const float4*)(_w);       wa1 = *(const float4*)(_w + 4); \
    wa2 = *(const float4*)(_w + 64);  wa3 = *(const float4*)(_w + 68); \
    wa4 = *(const float4*)(_w + 128); wa5 = *(const float4*)(_w + 132); \
    wa6 = *(const float4*)(_w + 192); wa7 = *(const float4*)(_w + 196); }
#define LOADB(Wp, c) { const float* _w = (Wp) + (c) * 256 + j0; \
    wb0 = *(const float4*)(_w);       wb1 = *(const float4*)(_w + 4); \
    wb2 = *(const float4*)(_w + 64);  wb3 = *(const float4*)(_w + 68); \
    wb4 = *(const float4*)(_w + 128); wb5 = *(const float4*)(_w + 132); \
    wb6 = *(const float4*)(_w + 192); wb7 = *(const float4*)(_w + 196); }
#define FMA1(xc, w0, w1) \
    acc[e][0] = fmaf(xc, w0.x, acc[e][0]); acc[e][1] = fmaf(xc, w0.y, acc[e][1]); \
    acc[e][2] = fmaf(xc, w0.z, acc[e][2]); acc[e][3] = fmaf(xc, w0.w, acc[e][3]); \
    acc[e][4] = fmaf(xc, w1.x, acc[e][4]); acc[e][5] = fmaf(xc, w1.y, acc[e][5]); \
    acc[e][6] = fmaf(xc, w1.z, acc[e][6]); acc[e][7] = fmaf(xc, w1.w, acc[e][7]);
#define FA(c) { _Pragma("unroll") for (int e = 0; e < 4; e++) { \
    const float4 xv = *(const float4*)&myA[e * 72 + (c) * 4]; \
    FMA1(xv.x, wa0, wa1) FMA1(xv.y, wa2, wa3) FMA1(xv.z, wa4, wa5) FMA1(xv.w, wa6, wa7) } }
#define FB(c) { _Pragma("unroll") for (int e = 0; e < 4; e++) { \
    const float4 xv = *(const float4*)&myA[e * 72 + (c) * 4]; \
    FMA1(xv.x, wb0, wb1) FMA1(xv.y, wb2, wb3) FMA1(xv.z, wb4, wb5) FMA1(xv.w, wb6, wb7) } }
#define INITACC(bb) { const float4 bv0 = *(const float4*)&(bb)[j0]; \
    const float4 bv1 = *(const float4*)&(bb)[j0 + 4]; \
    _Pragma("unroll") for (int e = 0; e < 4; e++) { \
        acc[e][0] = bv0.x; acc[e][1] = bv0.y; acc[e][2] = bv0.z; acc[e][3] = bv0.w; \
        acc[e][4] = bv1.x; acc[e][5] = bv1.y; acc[e][6] = bv1.z; acc[e][7] = bv1.w; } }
#define GELUSTORE() { _Pragma("unroll") for (int e = 0; e < 4; e++) { \
    float4 h0 = make_float4(gelu_f(acc[e][0]), gelu_f(acc[e][1]), gelu_f(acc[e][2]), gelu_f(acc[e][3])); \
    float4 h1 = make_float4(gelu_f(acc[e][4]), gelu_f(acc[e][5]), gelu_f(acc[e][6]), gelu_f(acc[e][7])); \
    *(float4*)&eA[ql * 1156 + (e0 + e) * 72 + j0] = h0; \
    *(float4*)&eA[ql * 1156 + (e0 + e) * 72 + j0 + 4] = h1; } }
#define LAYER16(W) \
    LOADA(W, 0); \
    LOADB(W, 1);  FA(0);  LOADA(W, 2);  FB(1); \
    LOADB(W, 3);  FA(2);  LOADA(W, 4);  FB(3); \
    LOADB(W, 5);  FA(4);  LOADA(W, 6);  FB(5); \
    LOADB(W, 7);  FA(6);  LOADA(W, 8);  FB(7); \
    LOADB(W, 9);  FA(8);  LOADA(W, 10); FB(9); \
    LOADB(W, 11); FA(10); LOADA(W, 12); FB(11); \
    LOADB(W, 13); FA(12); LOADA(W, 14); FB(13); \
    LOADB(W, 15); FA(14); FB(15);
#define LAYER18(W) \
    LOADA(W, 0); \
    LOADB(W, 1);  FA(0);  LOADA(W, 2);  FB(1); \
    LOADB(W, 3);  FA(2);  LOADA(W, 4);  FB(3); \
    LOADB(W, 5);  FA(4);  LOADA(W, 6);  FB(5); \
    LOADB(W, 7);  FA(6);  LOADA(W, 8);  FB(7); \
    LOADB(W, 9);  FA(8);  LOADA(W, 10); FB(9); \
    LOADB(W, 11); FA(10); LOADA(W, 12); FB(11); \
    LOADB(W, 13); FA(12); LOADA(W, 14); FB(13); \
    LOADB(W, 15); FA(14); LOADA(W, 16); FB(15); \
    LOADB(W, 17); FA(16); FB(17);

template <int MODE>
__global__ void __launch_bounds__(256, 4) k_edge(
    const int* __restrict__ idxb, const float* __restrict__ distb,
    const float* __restrict__ sigp,
    const float2* __restrict__ coords, const float4* __restrict__ gp,
    const float* __restrict__ feats,
    const float* __restrict__ W1p, const float* __restrict__ b1,
    const float* __restrict__ W2, const float* __restrict__ b2,
    const float* __restrict__ W3, const float* __restrict__ b3,
    float* __restrict__ outb, int Nq, int srcRows) {
    __shared__ __align__(16) float eA[8 * 1156];   // 8 q x (16 e x 72) + pad; reused as reduction buf
    __shared__ float wtsQ[8][16];
    __shared__ int   nidxQ[8][16];
    const int tid = threadIdx.x;
    const int wv = tid >> 6, lane = tid & 63;
    const int ql = lane >> 3, jg = lane & 7, j0 = jg * 8;
    const int e0 = wv * 4;                 // this wave's edge slice
    const int qw = blockIdx.x * 8;
    const float sig = *sigp;

    // ---- wave-local metadata + geometry (32 (q,e) pairs per wave)
    if (lane < 32) {
        int q = lane >> 2, e = e0 + (lane & 3);
        int gq = qw + q;
        int b = gq / Nq, p = gq - b * Nq;
        int si = idxb[gq * 16 + e];
        float d = distb[gq * 16 + e];
        nidxQ[q][e] = si;
        wtsQ[q][e] = expf(-d / sig);
        float qx, qy, sx, sy;
        if (MODE == 0) {
            float4 g = gp[p]; qx = g.x; qy = g.y;
            float2 cc = coords[(long)b * srcRows + si]; sx = cc.x; sy = cc.y;
        } else {
            float2 cc = coords[(long)b * Nq + p]; qx = cc.x; qy = cc.y;
            float4 g = gp[si]; sx = g.x; sy = g.y;
        }
        float* row = &eA[q * 1156 + e * 72];
        row[0] = qx; row[1] = qy; row[2] = sx; row[3] = sy;
        row[4] = qx - sx; row[5] = qy - sy; row[6] = d; row[7] = 0.f;
    }
    // ---- wave-local feats gather: 32 rows x 16 float4 = 512 slots
    for (int it = 0; it < 8; it++) {
        int slot = it * 64 + lane;
        int rowi = slot >> 4, f4 = slot & 15;
        int q = rowi >> 2, e = e0 + (rowi & 3);
        int gq = qw + q;
        int b = gq / Nq;
        int si = nidxQ[q][e];
        const float4 v = *(const float4*)&feats[((long)b * srcRows + si) * 64 + f4 * 4];
        *(float4*)&eA[q * 1156 + e * 72 + 8 + f4 * 4] = v;
    }
    // (no barrier: each wave touches only its own edge slice until the reduction)

    const float* myA = &eA[ql * 1156 + e0 * 72];
    float acc[4][8];
    float4 wa0, wa1, wa2, wa3, wa4, wa5, wa6, wa7;
    float4 wb0, wb1, wb2, wb3, wb4, wb5, wb6, wb7;

    // ---------- layer 1: x[0..71] via padded W1 (row 7 = 0), 18 c-iters
    INITACC(b1);
    LAYER18(W1p);
    GELUSTORE();
    // ---------- layer 2: x[0..63], 16 c-iters
    INITACC(b2);
    LAYER16(W2);
    GELUSTORE();
    // ---------- layer 3: x[0..63], no activation; weighted partial sum
    INITACC(b3);
    LAYER16(W3);
    float so[8];
#pragma unroll
    for (int jj = 0; jj < 8; jj++) so[jj] = 0.f;
#pragma unroll
    for (int e = 0; e < 4; e++) {
        float wvt = wtsQ[ql][e0 + e];
#pragma unroll
        for (int jj = 0; jj < 8; jj++) so[jj] = fmaf(wvt, acc[e][jj], so[jj]);
    }
    __syncthreads();        // all waves done with eA/wtsQ -> reduction
    *(float4*)&eA[wv * 512 + ql * 64 + j0]     = make_float4(so[0], so[1], so[2], so[3]);
    *(float4*)&eA[wv * 512 + ql * 64 + j0 + 4] = make_float4(so[4], so[5], so[6], so[7]);
    __syncthreads();
    for (int t2 = tid; t2 < 512; t2 += 256) {
        int q, col;
        if (MODE == 0) { q = t2 & 7; col = t2 >> 3; }
        else           { q = t2 >> 6; col = t2 & 63; }
        float s = eA[q * 64 + col] + eA[512 + q * 64 + col]
                + eA[1024 + q * 64 + col] + eA[1536 + q * 64 + col];
        float ws = 0.f;
#pragma unroll
        for (int e = 0; e < 16; e++) ws += wtsQ[q][e];
        float val = s / fmaxf(ws, 1e-6f);
        int gq = qw + q;
        if (MODE == 0) {
            int b = gq / Nq, p = gq - b * Nq;
            outb[((long)b * 64 + col) * 4096 + p] = val;   // transposed (b, col, p)
        } else {
            outb[(long)gq * 64 + col] = val;
        }
    }
}

// ---------------------------------------------------------------- transpose (B,R,C) -> (B,C,R)
__global__ void k_transp(const float* __restrict__ src, float* __restrict__ dst, int R, int C) {
    __shared__ float t[32][33];
    int b = blockIdx.z;
    int c0 = blockIdx.x * 32, r0 = blockIdx.y * 32;
    int tx = threadIdx.x, ty0 = threadIdx.y;    // (32,8)
    for (int yy = ty0; yy < 32; yy += 8) {
        int r = r0 + yy, c = c0 + tx;
        if (r < R && c < C) t[yy][tx] = src[((long)b * R + r) * C + c];
    }
    __syncthreads();
    for (int yy = ty0; yy < 32; yy += 8) {
        int c = c0 + yy, r = r0 + tx;
        if (r < R && c < C) dst[((long)b * C + c) * R + r] = t[tx][yy];
    }
}

// ---------------------------------------------------------------- FNO: truncated forward DFT
__global__ void __launch_bounds__(1024) k_f1(const float* __restrict__ x, float* __restrict__ Xh) {
    int blk = blockIdx.x;    // b*64 + ch
    int tid = threadIdx.x;   // 1024
    __shared__ __align__(16) float img[4096];
    __shared__ float Tre[64][12], Tim[64][12];
    __shared__ float cs[64], sn[64];
    if (tid < 64) {
        double a = (2.0 * PI_ / 64.0) * (double)tid;
        cs[tid] = (float)cos(a);
        sn[tid] = (float)sin(a);
    }
    ((float4*)img)[tid] = ((const float4*)(x + (long)blk * 4096))[tid];
    __syncthreads();
    if (tid < 768) {                             // (h, c)
        int h = tid / 12, c = tid - 12 * h;
        float re = 0.f, im = 0.f;
        for (int w = 0; w < 64; w++) {
            float v = img[h * 64 + w];
            int k = (c * w) & 63;
            re = fmaf(v, cs[k], re);
            im = fmaf(-v, sn[k], im);
        }
        Tre[h][c] = re; Tim[h][c] = im;
    }
    __syncthreads();
    if (tid < 288) {                             // (x24, c12)
        int xx = tid / 12, c = tid - 12 * xx;
        int r = (xx < 12) ? xx : (xx + 40);
        float re = 0.f, im = 0.f;
        for (int h = 0; h < 64; h++) {
            int k = (r * h) & 63;
            float cr = cs[k], si = sn[k];
            float a = Tre[h][c], bb = Tim[h][c];
            re += a * cr + bb * si;
            im += bb * cr - a * si;
        }
        Xh[((long)blk * 288 + tid) * 2] = re;
        Xh[((long)blk * 288 + tid) * 2 + 1] = im;
    }
}

// mode-mix: Yhat[b,o,m] = sum_i Wc[i,o,m] * Xhat[b,i,m]
__global__ void __launch_bounds__(256) k_f2(const float* __restrict__ Xh, const float* __restrict__ s1,
                                            const float* __restrict__ s2, float* __restrict__ Yh) {
    int m = blockIdx.x;                  // 0..287
    int xx = m / 12, y = m - 12 * xx;
    const float* W; int xw;
    if (xx < 12) { W = s1; xw = xx; } else { W = s2; xw = xx - 12; }
    __shared__ float xr[128], xi[128];
    __shared__ float pr[256], pi[256];
    int tid = threadIdx.x;               // 256
    if (tid < 128) {
        int bb = tid >> 6, i = tid & 63;
        xr[tid] = Xh[(((long)bb * 64 + i) * 288 + m) * 2];
        xi[tid] = Xh[(((long)bb * 64 + i) * 288 + m) * 2 + 1];
    }
    __syncthreads();
    int half = tid >> 7;
    int t2 = tid & 127;
    int bb = t2 >> 6, o = t2 & 63;
    float re = 0.f, im = 0.f;
    for (int i = half * 32; i < half * 32 + 32; i++) {
        long wb = (long)i * 18432 + (long)o * 288 + xw * 24 + y * 2;
        float wr = W[wb], wi = W[wb + 1];
        float a = xr[bb * 64 + i], cc = xi[bb * 64 + i];
        re += a * wr - cc * wi;
        im += a * wi + cc * wr;
    }
    pr[tid] = re; pi[tid] = im;
    __syncthreads();
    if (tid < 128) {
        float re2 = pr[tid] + pr[tid + 128];
        float im2 = pi[tid] + pi[tid + 128];
        Yh[(((long)bb * 64 + o) * 288 + m) * 2] = re2;
        Yh[(((long)bb * 64 + o) * 288 + m) * 2 + 1] = im2;
    }
}

// inverse DFT + pointwise conv + bias + InstanceNorm + GELU, fused per (b, out-channel)
__global__ void __launch_bounds__(1024) k_f3(const float* __restrict__ Yh, const float* __restrict__ x,
                                             const float* __restrict__ pwW, const float* __restrict__ pwb,
                                             float* __restrict__ xo) {
    int blk = blockIdx.x;
    int b = blk >> 6, o = blk & 63;
    int tid = threadIdx.x;   // 1024; each thread owns 4 consecutive pixels
    __shared__ float yre[288], yim[288];
    __shared__ float Qre[64][12], Qim[64][12];
    __shared__ float cs[64], sn[64];
    __shared__ float red[1024];
    if (tid < 64) {
        double a = (2.0 * PI_ / 64.0) * (double)tid;
        cs[tid] = (float)cos(a);
        sn[tid] = (float)sin(a);
    }
    if (tid < 288) {
        yre[tid] = Yh[((long)blk * 288 + tid) * 2];
        yim[tid] = Yh[((long)blk * 288 + tid) * 2 + 1];
    }
    __syncthreads();
    if (tid < 768) {    // (h, c): complex ifft along rows (1/64 scale)
        int h = tid / 12, c = tid - 12 * h;
        float re = 0.f, im = 0.f;
#pragma unroll
        for (int xx = 0; xx < 24; xx++) {
            int r = (xx < 12) ? xx : (xx + 40);
            int k = (r * h) & 63;
            float wr = cs[k], wi = sn[k];
            float a = yre[xx * 12 + c], bb = yim[xx * 12 + c];
            re += a * wr - bb * wi;
            im += a * wi + bb * wr;
        }
        Qre[h][c] = re * (1.0f / 64.0f);
        Qim[h][c] = im * (1.0f / 64.0f);
    }
    __syncthreads();
    float bias = pwb[o];
    int h = tid >> 4;
    int w0 = (tid & 15) * 4;
    float sp0, sp1, sp2, sp3;
    {
        float base = Qre[h][0];
        sp0 = sp1 = sp2 = sp3 = base;
#pragma unroll
        for (int c = 1; c < 12; c++) {
            float qr = Qre[h][c], qi = Qim[h][c];
            int k0 = (c * w0) & 63, k1 = (c * (w0 + 1)) & 63;
            int k2 = (c * (w0 + 2)) & 63, k3 = (c * (w0 + 3)) & 63;
            sp0 += 2.0f * (qr * cs[k0] - qi * sn[k0]);
            sp1 += 2.0f * (qr * cs[k1] - qi * sn[k1]);
            sp2 += 2.0f * (qr * cs[k2] - qi * sn[k2]);
            sp3 += 2.0f * (qr * cs[k3] - qi * sn[k3]);
        }
    }
    float a0 = sp0 * (1.0f / 64.0f) + bias;
    float a1 = sp1 * (1.0f / 64.0f) + bias;
    float a2 = sp2 * (1.0f / 64.0f) + bias;
    float a3 = sp3 * (1.0f / 64.0f) + bias;
    const float* xb = x + ((long)b * 64) * 4096 + tid * 4;
    for (int i = 0; i < 64; i++) {
        float wv = pwW[o * 64 + i];
        const float4 xv = *(const float4*)(xb + (long)i * 4096);
        a0 = fmaf(xv.x, wv, a0);
        a1 = fmaf(xv.y, wv, a1);
        a2 = fmaf(xv.z, wv, a2);
        a3 = fmaf(xv.w, wv, a3);
    }
    red[tid] = a0 + a1 + a2 + a3;
    __syncthreads();
    for (int d = 512; d > 0; d >>= 1) { if (tid < d) red[tid] += red[tid + d]; __syncthreads(); }
    float mu = red[0] * (1.0f / 4096.0f);
    __syncthreads();
    float d0 = a0 - mu, d1 = a1 - mu, d2 = a2 - mu, d3 = a3 - mu;
    red[tid] = d0 * d0 + d1 * d1 + d2 * d2 + d3 * d3;
    __syncthreads();
    for (int d = 512; d > 0; d >>= 1) { if (tid < d) red[tid] += red[tid + d]; __syncthreads(); }
    float var = red[0] * (1.0f / 4096.0f);
    float inv = 1.0f / sqrtf(var + 1e-5f);
    float4 ov = make_float4(gelu_f(d0 * inv), gelu_f(d1 * inv), gelu_f(d2 * inv), gelu_f(d3 * inv));
    *(float4*)&xo[(long)blk * 4096 + tid * 4] = ov;
}

// ---------------------------------------------------------------- projection MLP (64 -> 64 -> 3)
__global__ void __launch_bounds__(256) k_proj(
    const float* __restrict__ y, const float* __restrict__ W1, const float* __restrict__ b1,
    const float* __restrict__ W2, const float* __restrict__ b2, float* __restrict__ out) {
    __shared__ __align__(16) float yr[4][64];
    __shared__ float h[4][64];
    int ql = threadIdx.x >> 6, j = threadIdx.x & 63;
    long node = (long)blockIdx.x * 4 + ql;
    yr[ql][j] = y[node * 64 + j];
    __syncthreads();
    float a = b1[j];
    for (int k = 0; k < 64; k += 4) {
        float w0 = W1[(k + 0) * 64 + j], w1 = W1[(k + 1) * 64 + j];
        float w2 = W1[(k + 2) * 64 + j], w3 = W1[(k + 3) * 64 + j];
        const float4 hv = *(const float4*)&yr[ql][k];
        a = fmaf(hv.x, w0, fmaf(hv.y, w1, fmaf(hv.z, w2, fmaf(hv.w, w3, a))));
    }
    h[ql][j] = gelu_f(a);
    __syncthreads();
    if (j < 3) {
        float a2 = b2[j];
        for (int k = 0; k < 64; k++) a2 = fmaf(h[ql][k], W2[k * 3 + j], a2);
        out[node * 3 + j] = a2;
    }
}

// ---------------------------------------------------------------- launch
extern "C" void kernel_launch(void* const* d_in, const int* in_sizes, int n_in,
                              void* d_out, int out_size, void* d_ws, size_t ws_size,
                              hipStream_t stream) {
    (void)in_sizes; (void)n_in; (void)out_size; (void)ws_size;
    const float* coords   = (const float*)d_in[0];
    const float* features = (const float*)d_in[1];
    const float* lift_W1 = (const float*)d_in[2];
    const float* lift_b1 = (const float*)d_in[3];
    const float* lift_W2 = (const float*)d_in[4];
    const float* lift_b2 = (const float*)d_in[5];
    const float* gin_W1 = (const float*)d_in[6];
    const float* gin_b1 = (const float*)d_in[7];
    const float* gin_W2 = (const float*)d_in[8];
    const float* gin_b2 = (const float*)d_in[9];
    const float* gin_W3 = (const float*)d_in[10];
    const float* gin_b3 = (const float*)d_in[11];
    const float* spec1 = (const float*)d_in[12];
    const float* spec2 = (const float*)d_in[13];
    const float* pw_W  = (const float*)d_in[14];
    const float* pw_b  = (const float*)d_in[15];
    const float* gout_W1 = (const float*)d_in[16];
    const float* gout_b1 = (const float*)d_in[17];
    const float* gout_W2 = (const float*)d_in[18];
    const float* gout_b2 = (const float*)d_in[19];
    const float* gout_W3 = (const float*)d_in[20];
    const float* gout_b3 = (const float*)d_in[21];
    const float* proj_W1 = (const float*)d_in[22];
    const float* proj_b1 = (const float*)d_in[23];
    const float* proj_W2 = (const float*)d_in[24];
    const float* proj_b2 = (const float*)d_in[25];

    char* ws = (char*)d_ws;
    size_t off = 0;
    auto alloc = [&](size_t bytes) -> char* {
        char* p = ws + off;
        off = (off + bytes + 255) & ~(size_t)255;
        return p;
    };
    float4* grid_pack = (float4*)alloc((size_t)NG * 16);
    float*  feat      = (float*)alloc((size_t)B_ * N_ * 64 * 4);
    int*    bin_cnt   = (int*)alloc((size_t)B_ * 4096 * 4);
    int*    bin_fill  = (int*)alloc((size_t)B_ * 4096 * 4);
    int*    bin_off   = (int*)alloc((size_t)B_ * 4097 * 4);
    float4* srt       = (float4*)alloc((size_t)B_ * N_ * 16);
    int*    idx_in    = (int*)alloc((size_t)B_ * NG * 16 * 4);
    float*  dist_in   = (float*)alloc((size_t)B_ * NG * 16 * 4);
    float*  lastd_in  = (float*)alloc((size_t)B_ * NG * 4);
    float*  sig_in    = (float*)alloc(256);
    float*  w1p_in    = (float*)alloc(4608 * 4);
    float*  w1p_out   = (float*)alloc(4608 * 4);
    float*  xb0       = (float*)alloc((size_t)B_ * 64 * NG * 4);
    float*  xb1       = (float*)alloc((size_t)B_ * 64 * NG * 4);
    float*  Xh        = (float*)alloc((size_t)B_ * 64 * 288 * 2 * 4);
    float*  Yh        = (float*)alloc((size_t)B_ * 64 * 288 * 2 * 4);
    float*  g2        = (float*)alloc((size_t)B_ * NG * 64 * 4);
    int*    idx_out   = (int*)alloc((size_t)B_ * N_ * 16 * 4);
    float*  dist_out  = (float*)alloc((size_t)B_ * N_ * 16 * 4);
    float*  lastd_out = (float*)alloc((size_t)B_ * N_ * 4);
    float*  sig_out   = (float*)alloc(256);
    float*  ybuf      = (float*)alloc((size_t)B_ * N_ * 64 * 4);

    hipMemsetAsync(bin_cnt, 0, (size_t)B_ * 4096 * 4, stream);
    hipMemsetAsync(bin_fill, 0, (size_t)B_ * 4096 * 4, stream);

    k_padw1<<<36, 256, 0, stream>>>(gin_W1, gout_W1, w1p_in, w1p_out);
    k_lift<<<(B_ * N_) / 4, 256, 0, stream>>>(features, lift_W1, lift_b1, lift_W2, lift_b2, feat);
    k_bincount<<<(B_ * N_) / 256, 256, 0, stream>>>((const float2*)coords, bin_cnt, grid_pack);
    k_binscan<<<B_, 1024, 0, stream>>>(bin_cnt, bin_off);
    k_binscatter<<<(B_ * N_) / 256, 256, 0, stream>>>((const float2*)coords, bin_off, bin_fill, srt);
    k_knn_in<<<(B_ * NG * 64) / 256, 256, 0, stream>>>(grid_pack, srt, bin_off, idx_in, dist_in, lastd_in);
    k_median_bis<<<1, 1024, 0, stream>>>(lastd_in, B_ * NG, sig_in);
    k_edge<0><<<(B_ * NG) / 8, 256, 0, stream>>>(idx_in, dist_in, sig_in,
        (const float2*)coords, grid_pack, feat,
        w1p_in, gin_b1, gin_W2, gin_b2, gin_W3, gin_b3, xb0, NG, N_);
    float* xc = xb0; float* xn = xb1;
    for (int d = 0; d < 3; d++) {
        k_f1<<<B_ * 64, 1024, 0, stream>>>(xc, Xh);
        k_f2<<<288, 256, 0, stream>>>(Xh, spec1 + (size_t)d * 1179648, spec2 + (size_t)d * 1179648, Yh);
        k_f3<<<B_ * 64, 1024, 0, stream>>>(Yh, xc, pw_W + (size_t)d * 4096, pw_b + (size_t)d * 64, xn);
        float* tmp = xc; xc = xn; xn = tmp;
    }
    {
        dim3 g(NG / 32, 64 / 32, B_); dim3 t(32, 8);
        k_transp<<<g, t, 0, stream>>>(xc, g2, 64, NG);
    }
    k_knn_out<<<(B_ * N_ * 64) / 256, 256, 0, stream>>>((const float2*)coords, grid_pack, idx_out, dist_out, lastd_out);
    k_median_bis<<<1, 1024, 0, stream>>>(lastd_out, B_ * N_, sig_out);
    k_edge<1><<<(B_ * N_) / 8, 256, 0, stream>>>(idx_out, dist_out, sig_out,
        (const float2*)coords, grid_pack, g2,
        w1p_out, gout_b1, gout_W2, gout_b2, gout_W3, gout_b3, ybuf, N_, NG);
    k_proj<<<(B_ * N_) / 4, 256, 0, stream>>>(ybuf, proj_W1, proj_b1, proj_W2, proj_b2, (float*)d_out);
}

// Round 10
// 569.063 us; speedup vs baseline: 20.2937x; 20.2937x over previous
//
#include <hip/hip_runtime.h>
#include <math.h>

#define B_ 2
#define N_ 8192          // points per batch
#define G_ 64
#define NG 4096          // G*G latent grid points
#define WID_ 64
#define K_ 16
#define CIN_ 6
#define COUT_ 3
#define PI_ 3.14159265358979323846

typedef unsigned long long u64k;

// ---------------------------------------------------------------- helpers
__device__ __forceinline__ float gelu_f(float x) {
    return 0.5f * x * (1.0f + erff(x * 0.70710678118654752440f));
}
__device__ __forceinline__ int cellof(float v) {
    int c = (int)floorf((v + 1.0f) * 32.0f);
    return min(63, max(0, c));
}
__device__ __forceinline__ u64k umin64(u64k a, u64k b) { return a < b ? a : b; }
__device__ __forceinline__ u64k umax64(u64k a, u64k b) { return a < b ? b : a; }
__device__ __forceinline__ u64k shflxor64(u64k v, int m) {
    return (u64k)__shfl_xor((long long)v, m, 64);
}
__device__ __forceinline__ void bsort64(u64k& key, int lane) {
#pragma unroll
    for (int sz = 2; sz <= 64; sz <<= 1) {
#pragma unroll
        for (int j = sz >> 1; j >= 1; j >>= 1) {
            u64k o = shflxor64(key, j);
            bool keep_min = ((lane & j) == 0) == ((lane & sz) == 0);
            key = keep_min ? umin64(key, o) : umax64(key, o);
        }
    }
}
__device__ __forceinline__ void bmerge_into(u64k& R, u64k key, int lane) {
    u64k o = shflxor64(key, 63);
    u64k L = umin64(R, o);
#pragma unroll
    for (int j = 32; j >= 1; j >>= 1) {
        u64k t = shflxor64(L, j);
        L = ((lane & j) == 0) ? umin64(L, t) : umax64(L, t);
    }
    R = L;
}

// ---------------------------------------------------------------- binning (+ grid gen fused)
__global__ void k_bincount(const float2* __restrict__ coords, int* __restrict__ cnt,
                           float4* __restrict__ gp) {
    int t = blockIdx.x * blockDim.x + threadIdx.x;
    if (t < NG) {        // numpy linspace semantics grid gen
        int i = t >> 6, j = t & 63;
        double st = 2.0 / 63.0;
        float gx = (i == 63) ? 1.0f : (float)(-1.0 + st * (double)i);
        float gy = (j == 63) ? 1.0f : (float)(-1.0 + st * (double)j);
        float s2 = __fadd_rn(__fmul_rn(gx, gx), __fmul_rn(gy, gy));
        gp[t] = make_float4(gx, gy, s2, 0.f);
    }
    if (t >= B_ * N_) return;
    float2 c = coords[t];
    int b = t >> 13;
    int cell = cellof(c.x) * 64 + cellof(c.y);
    atomicAdd(&cnt[b * 4096 + cell], 1);
}
__global__ void k_binscan(const int* __restrict__ cnt, int* __restrict__ offs) {
    int b = blockIdx.x, t = threadIdx.x;    // 1024 threads
    __shared__ int s[1024];
    int4 v = ((const int4*)(cnt + b * 4096))[t];
    int sum = v.x + v.y + v.z + v.w;
    s[t] = sum;
    __syncthreads();
    for (int d = 1; d < 1024; d <<= 1) {
        int x = (t >= d) ? s[t - d] : 0;
        __syncthreads();
        s[t] += x;
        __syncthreads();
    }
    int incl = s[t], excl = incl - sum;
    int* ob = offs + b * 4097;
    ob[4 * t] = excl; ob[4 * t + 1] = excl + v.x;
    ob[4 * t + 2] = excl + v.x + v.y; ob[4 * t + 3] = excl + v.x + v.y + v.z;
    if (t == 1023) ob[4096] = incl;
}
__global__ void k_binscatter(const float2* __restrict__ coords, const int* __restrict__ offs,
                             int* __restrict__ fill, float4* __restrict__ srt) {
    int t = blockIdx.x * blockDim.x + threadIdx.x;
    if (t >= B_ * N_) return;
    float2 c = coords[t];
    int b = t >> 13, n = t & 8191;
    int cell = cellof(c.x) * 64 + cellof(c.y);
    int pos = offs[b * 4097 + cell] + atomicAdd(&fill[b * 4096 + cell], 1);
    float s2 = __fadd_rn(__fmul_rn(c.x, c.x), __fmul_rn(c.y, c.y));
    srt[b * N_ + pos] = make_float4(c.x, c.y, s2, __int_as_float(n));
}

// ---------------------------------------------------------------- lift MLP
__global__ void __launch_bounds__(256) k_lift(
    const float* __restrict__ fin, const float* __restrict__ W1,
    const float* __restrict__ b1, const float* __restrict__ W2,
    const float* __restrict__ b2, float* __restrict__ fout) {
    __shared__ float xr[4][8];
    __shared__ __align__(16) float h[4][64];
    int ql = threadIdx.x >> 6, j = threadIdx.x & 63;
    int node = blockIdx.x * 4 + ql;
    if (j < CIN_) xr[ql][j] = fin[node * CIN_ + j];
    __syncthreads();
    float a = b1[j];
#pragma unroll
    for (int i = 0; i < CIN_; i++) a = fmaf(xr[ql][i], W1[i * 64 + j], a);
    h[ql][j] = gelu_f(a);
    __syncthreads();
    float a2 = b2[j];
    for (int k = 0; k < 64; k += 4) {
        float w0 = W2[(k + 0) * 64 + j], w1 = W2[(k + 1) * 64 + j];
        float w2 = W2[(k + 2) * 64 + j], w3 = W2[(k + 3) * 64 + j];
        const float4 hv = *(const float4*)&h[ql][k];
        a2 = fmaf(hv.x, w0, fmaf(hv.y, w1, fmaf(hv.z, w2, fmaf(hv.w, w3, a2))));
    }
    fout[node * 64 + j] = a2;
}

// ---------------------------------------------------------------- kNN grid->points: one wave per query
__global__ void __launch_bounds__(256) k_knn_in(
    const float4* __restrict__ gp, const float4* __restrict__ srt,
    const int* __restrict__ offs, int* __restrict__ oidx,
    float* __restrict__ odist, float* __restrict__ lastd) {
    int lane = threadIdx.x & 63;
    int w = (blockIdx.x * blockDim.x + threadIdx.x) >> 6;
    int b = w >> 12, p = w & 4095;
    float4 q = gp[p];
    float qx = q.x, qy = q.y, q2 = q.z;
    int cqx = cellof(qx), cqy = cellof(qy);
    const float4* S = srt + b * N_;
    const int* OF = offs + b * 4097;

    u64k R = ~0ull;
    u64k pend = ~0ull;
    int fill = 0;

    auto flush = [&]() {
        bsort64(pend, lane);
        bmerge_into(R, pend, lane);
        pend = ~0ull;
        fill = 0;
    };
    auto feed = [&](int s0, int s1) {
        int cnt = s1 - s0;
        while (cnt > 0) {
            int take = min(cnt, 64 - fill);
            int t = lane - fill;
            if (t >= 0 && t < take) {
                float4 sp = S[s0 + t];
                float dot = __fadd_rn(__fmul_rn(qx, sp.x), __fmul_rn(qy, sp.y));
                float d2 = __fsub_rn(__fadd_rn(q2, sp.z), 2.0f * dot);
                d2 = fmaxf(d2, 0.0f);
                pend = ((u64k)__float_as_uint(d2) << 32) | (unsigned)__float_as_int(sp.w);
            }
            fill += take; s0 += take; cnt -= take;
            if (fill == 64) flush();
        }
    };

    {
        int xa = max(cqx - 2, 0), xb = min(cqx + 2, 63);
        int ya = max(cqy - 2, 0), yb = min(cqy + 2, 63);
        for (int cx = xa; cx <= xb; cx++) feed(OF[cx * 64 + ya], OF[cx * 64 + yb + 1]);
    }
    int r = 2;
    while (true) {
        if (fill) flush();
        u64k T = (u64k)__shfl((long long)R, 15, 64);
        float d16 = __uint_as_float((unsigned)(T >> 32));
        float bm = (float)r * 0.03125f;
        if (d16 < bm * bm - 1e-5f) break;
        if (cqx - r <= 0 && cqx + r >= 63 && cqy - r <= 0 && cqy + r >= 63) break;
        r++;
        int ya = max(cqy - r, 0), yb = min(cqy + r, 63);
        if (cqx - r >= 0)  { int c0 = (cqx - r) * 64; feed(OF[c0 + ya], OF[c0 + yb + 1]); }
        if (cqx + r <= 63) { int c0 = (cqx + r) * 64; feed(OF[c0 + ya], OF[c0 + yb + 1]); }
        int xa2 = max(cqx - r + 1, 0), xb2 = min(cqx + r - 1, 63);
        for (int cx = xa2; cx <= xb2; cx++) {
            if (cqy - r >= 0)  { int cc = cx * 64 + cqy - r; feed(OF[cc], OF[cc + 1]); }
            if (cqy + r <= 63) { int cc = cx * 64 + cqy + r; feed(OF[cc], OF[cc + 1]); }
        }
    }
    if (lane < 16) {
        float d2 = __uint_as_float((unsigned)(R >> 32));
        float d = sqrtf(d2);
        oidx[w * 16 + lane] = (int)(unsigned)(R & 0xffffffffu);
        odist[w * 16 + lane] = d;
        if (lane == 15) lastd[w] = d;
    }
}

// ---------------------------------------------------------------- kNN points->grid: one wave per query
__global__ void __launch_bounds__(256) k_knn_out(
    const float2* __restrict__ coords, const float4* __restrict__ gp,
    int* __restrict__ oidx, float* __restrict__ odist, float* __restrict__ lastd) {
    int lane = threadIdx.x & 63;
    int w = (blockIdx.x * blockDim.x + threadIdx.x) >> 6;
    float2 c = coords[w];
    float qx = c.x, qy = c.y;
    float q2 = __fadd_rn(__fmul_rn(qx, qx), __fmul_rn(qy, qy));
    int i0 = (int)floorf((qx + 1.0f) * 31.5f);
    int j0 = (int)floorf((qy + 1.0f) * 31.5f);
    int li = min(max(i0 - 3, 0), 56);
    int lj = min(max(j0 - 3, 0), 56);
    int p = (li + (lane >> 3)) * 64 + (lj + (lane & 7));
    float4 sp = gp[p];
    float dot = __fadd_rn(__fmul_rn(qx, sp.x), __fmul_rn(qy, sp.y));
    float d2 = fmaxf(__fsub_rn(__fadd_rn(q2, sp.z), 2.0f * dot), 0.0f);
    u64k key = ((u64k)__float_as_uint(d2) << 32) | (unsigned)p;
    bsort64(key, lane);
    if (lane < 16) {
        float dd = sqrtf(__uint_as_float((unsigned)(key >> 32)));
        oidx[w * 16 + lane] = (int)(unsigned)(key & 0xffffffffu);
        odist[w * 16 + lane] = dd;
        if (lane == 15) lastd[w] = dd;
    }
}

// ---------------------------------------------------------------- exact lower-median via 32-step bisection
__global__ void __launch_bounds__(1024) k_median_bis(
    const float* __restrict__ vals, int n, float* __restrict__ sig) {
    __shared__ int wred[2][16];
    int tid = threadIdx.x;
    int lane = tid & 63, wv = tid >> 6;
    int cnt_per = n >> 10;           // 8 or 16
    unsigned v[16];
    for (int i = 0; i < cnt_per; i++) v[i] = __float_as_uint(vals[tid + (i << 10)]);
    int r = (n - 1) >> 1;
    unsigned prefix = 0;
    for (int bit = 31; bit >= 0; bit--) {
        unsigned cand = prefix | (1u << bit);
        int c = 0;
        for (int i = 0; i < cnt_per; i++) c += (v[i] < cand) ? 1 : 0;
        for (int o = 32; o >= 1; o >>= 1) c += __shfl_down(c, o, 64);
        int buf = bit & 1;
        if (lane == 0) wred[buf][wv] = c;
        __syncthreads();
        int tot = 0;
#pragma unroll
        for (int k = 0; k < 16; k++) tot += wred[buf][k];
        prefix = (tot <= r) ? cand : prefix;
    }
    if (tid == 0) *sig = fmaxf(__uint_as_float(prefix), 1e-6f);
}

// ---------------------------------------------------------------- edge MLP + weighted aggregation (v4, launch_bounds(256,2))
// One block (4 waves) per 8 queries; wave wv owns edge slice wv*4..+3
// end-to-end (staging + 3 layers) -> NO mid-kernel barriers. Weights come
// from GLOBAL (L1-resident, vmem pipe); only x fragments go through LDS.
// launch_bounds min-waves = 2 (NOT 4): occupancy is LDS-capped at 4 blocks/CU
// anyway, and the (256,4) bound made the allocator pin VGPRs at 64 and (in
// v5/v6) spill to scratch; (256,2) gives the scheduler a real register budget
// to hoist weight loads (v3 under (256,2) allocated 88 VGPRs with no spill).
template <int MODE>
__global__ void __launch_bounds__(256, 2) k_edge(
    const int* __restrict__ idxb, const float* __restrict__ distb,
    const float* __restrict__ sigp,
    const float2* __restrict__ coords, const float4* __restrict__ gp,
    const float* __restrict__ feats,
    const float* __restrict__ W1, const float* __restrict__ b1,
    const float* __restrict__ W2, const float* __restrict__ b2,
    const float* __restrict__ W3, const float* __restrict__ b3,
    float* __restrict__ outb, int Nq, int srcRows) {
    __shared__ __align__(16) float eA[8 * 1156];   // 8 q x (16 e x 72) + pad; reused as reduction buf
    __shared__ float wtsQ[8][16];
    __shared__ int   nidxQ[8][16];
    const int tid = threadIdx.x;
    const int wv = tid >> 6, lane = tid & 63;
    const int ql = lane >> 3, jg = lane & 7, j0 = jg * 8;
    const int e0 = wv * 4;                 // this wave's edge slice
    const int qw = blockIdx.x * 8;
    const float sig = *sigp;

    // ---- wave-local metadata + geometry (32 (q,e) pairs per wave)
    if (lane < 32) {
        int q = lane >> 2, e = e0 + (lane & 3);
        int gq = qw + q;
        int b = gq / Nq, p = gq - b * Nq;
        int si = idxb[gq * 16 + e];
        float d = distb[gq * 16 + e];
        nidxQ[q][e] = si;
        wtsQ[q][e] = expf(-d / sig);
        float qx, qy, sx, sy;
        if (MODE == 0) {
            float4 g = gp[p]; qx = g.x; qy = g.y;
            float2 cc = coords[(long)b * srcRows + si]; sx = cc.x; sy = cc.y;
        } else {
            float2 cc = coords[(long)b * Nq + p]; qx = cc.x; qy = cc.y;
            float4 g = gp[si]; sx = g.x; sy = g.y;
        }
        float* row = &eA[q * 1156 + e * 72];
        row[0] = qx; row[1] = qy; row[2] = sx; row[3] = sy;
        row[4] = qx - sx; row[5] = qy - sy; row[6] = d; row[7] = 0.f;
    }
    // ---- wave-local feats gather: 32 rows x 16 float4 = 512 slots
    for (int it = 0; it < 8; it++) {
        int slot = it * 64 + lane;
        int rowi = slot >> 4, f4 = slot & 15;
        int q = rowi >> 2, e = e0 + (rowi & 3);
        int gq = qw + q;
        int b = gq / Nq;
        int si = nidxQ[q][e];
        const float4 v = *(const float4*)&feats[((long)b * srcRows + si) * 64 + f4 * 4];
        *(float4*)&eA[q * 1156 + e * 72 + 8 + f4 * 4] = v;
    }
    // (no barrier: each wave touches only its own edge slice until the reduction)

    const float* myA = &eA[ql * 1156 + e0 * 72];
    float acc[4][8];
    // ---------- layer 1: x[0..71] (x[7]==0; W1 rows skip slot 7)
    {
        float4 bv0 = *(const float4*)&b1[j0], bv1 = *(const float4*)&b1[j0 + 4];
        float bj[8] = {bv0.x, bv0.y, bv0.z, bv0.w, bv1.x, bv1.y, bv1.z, bv1.w};
#pragma unroll
        for (int e = 0; e < 4; e++)
#pragma unroll
            for (int jj = 0; jj < 8; jj++) acc[e][jj] = bj[jj];
        for (int c = 0; c < 18; c++) {
            float w[4][8];
#pragma unroll
            for (int rr = 0; rr < 4; rr++) {
                int t = c * 4 + rr;
                int wrow = t - (t > 6);
                float4 a = *(const float4*)&W1[wrow * 64 + j0];
                float4 bq = *(const float4*)&W1[wrow * 64 + j0 + 4];
                if (t == 7) { a = make_float4(0.f, 0.f, 0.f, 0.f); bq = a; }
                w[rr][0] = a.x; w[rr][1] = a.y; w[rr][2] = a.z; w[rr][3] = a.w;
                w[rr][4] = bq.x; w[rr][5] = bq.y; w[rr][6] = bq.z; w[rr][7] = bq.w;
            }
#pragma unroll
            for (int e = 0; e < 4; e++) {
                const float4 xv = *(const float4*)&myA[e * 72 + c * 4];
                const float xs[4] = {xv.x, xv.y, xv.z, xv.w};
#pragma unroll
                for (int rr = 0; rr < 4; rr++)
#pragma unroll
                    for (int jj = 0; jj < 8; jj++)
                        acc[e][jj] = fmaf(xs[rr], w[rr][jj], acc[e][jj]);
            }
        }
    }
#pragma unroll
    for (int e = 0; e < 4; e++) {
        float4 h0 = make_float4(gelu_f(acc[e][0]), gelu_f(acc[e][1]),
                                gelu_f(acc[e][2]), gelu_f(acc[e][3]));
        float4 h1 = make_float4(gelu_f(acc[e][4]), gelu_f(acc[e][5]),
                                gelu_f(acc[e][6]), gelu_f(acc[e][7]));
        *(float4*)&eA[ql * 1156 + (e0 + e) * 72 + j0] = h0;
        *(float4*)&eA[ql * 1156 + (e0 + e) * 72 + j0 + 4] = h1;
    }
    // ---------- layer 2: x[0..63]
    {
        float4 bv0 = *(const float4*)&b2[j0], bv1 = *(const float4*)&b2[j0 + 4];
        float bj[8] = {bv0.x, bv0.y, bv0.z, bv0.w, bv1.x, bv1.y, bv1.z, bv1.w};
#pragma unroll
        for (int e = 0; e < 4; e++)
#pragma unroll
            for (int jj = 0; jj < 8; jj++) acc[e][jj] = bj[jj];
        for (int c = 0; c < 16; c++) {
            float w[4][8];
#pragma unroll
            for (int rr = 0; rr < 4; rr++) {
                float4 a = *(const float4*)&W2[(c * 4 + rr) * 64 + j0];
                float4 bq = *(const float4*)&W2[(c * 4 + rr) * 64 + j0 + 4];
                w[rr][0] = a.x; w[rr][1] = a.y; w[rr][2] = a.z; w[rr][3] = a.w;
                w[rr][4] = bq.x; w[rr][5] = bq.y; w[rr][6] = bq.z; w[rr][7] = bq.w;
            }
#pragma unroll
            for (int e = 0; e < 4; e++) {
                const float4 xv = *(const float4*)&myA[e * 72 + c * 4];
                const float xs[4] = {xv.x, xv.y, xv.z, xv.w};
#pragma unroll
                for (int rr = 0; rr < 4; rr++)
#pragma unroll
                    for (int jj = 0; jj < 8; jj++)
                        acc[e][jj] = fmaf(xs[rr], w[rr][jj], acc[e][jj]);
            }
        }
    }
#pragma unroll
    for (int e = 0; e < 4; e++) {
        float4 h0 = make_float4(gelu_f(acc[e][0]), gelu_f(acc[e][1]),
                                gelu_f(acc[e][2]), gelu_f(acc[e][3]));
        float4 h1 = make_float4(gelu_f(acc[e][4]), gelu_f(acc[e][5]),
                                gelu_f(acc[e][6]), gelu_f(acc[e][7]));
        *(float4*)&eA[ql * 1156 + (e0 + e) * 72 + j0] = h0;
        *(float4*)&eA[ql * 1156 + (e0 + e) * 72 + j0 + 4] = h1;
    }
    // ---------- layer 3: x[0..63], no activation; weighted partial sum
    float so[8];
#pragma unroll
    for (int jj = 0; jj < 8; jj++) so[jj] = 0.f;
    {
        float4 bv0 = *(const float4*)&b3[j0], bv1 = *(const float4*)&b3[j0 + 4];
        float bj[8] = {bv0.x, bv0.y, bv0.z, bv0.w, bv1.x, bv1.y, bv1.z, bv1.w};
#pragma unroll
        for (int e = 0; e < 4; e++)
#pragma unroll
            for (int jj = 0; jj < 8; jj++) acc[e][jj] = bj[jj];
        for (int c = 0; c < 16; c++) {
            float w[4][8];
#pragma unroll
            for (int rr = 0; rr < 4; rr++) {
                float4 a = *(const float4*)&W3[(c * 4 + rr) * 64 + j0];
                float4 bq = *(const float4*)&W3[(c * 4 + rr) * 64 + j0 + 4];
                w[rr][0] = a.x; w[rr][1] = a.y; w[rr][2] = a.z; w[rr][3] = a.w;
                w[rr][4] = bq.x; w[rr][5] = bq.y; w[rr][6] = bq.z; w[rr][7] = bq.w;
            }
#pragma unroll
            for (int e = 0; e < 4; e++) {
                const float4 xv = *(const float4*)&myA[e * 72 + c * 4];
                const float xs[4] = {xv.x, xv.y, xv.z, xv.w};
#pragma unroll
                for (int rr = 0; rr < 4; rr++)
#pragma unroll
                    for (int jj = 0; jj < 8; jj++)
                        acc[e][jj] = fmaf(xs[rr], w[rr][jj], acc[e][jj]);
            }
        }
#pragma unroll
        for (int e = 0; e < 4; e++) {
            float wvt = wtsQ[ql][e0 + e];
#pragma unroll
            for (int jj = 0; jj < 8; jj++) so[jj] = fmaf(wvt, acc[e][jj], so[jj]);
        }
    }
    __syncthreads();        // all waves done with eA/wtsQ -> reduction
    *(float4*)&eA[wv * 512 + ql * 64 + j0]     = make_float4(so[0], so[1], so[2], so[3]);
    *(float4*)&eA[wv * 512 + ql * 64 + j0 + 4] = make_float4(so[4], so[5], so[6], so[7]);
    __syncthreads();
    for (int t2 = tid; t2 < 512; t2 += 256) {
        int q, col;
        if (MODE == 0) { q = t2 & 7; col = t2 >> 3; }
        else           { q = t2 >> 6; col = t2 & 63; }
        float s = eA[q * 64 + col] + eA[512 + q * 64 + col]
                + eA[1024 + q * 64 + col] + eA[1536 + q * 64 + col];
        float ws = 0.f;
#pragma unroll
        for (int e = 0; e < 16; e++) ws += wtsQ[q][e];
        float val = s / fmaxf(ws, 1e-6f);
        int gq = qw + q;
        if (MODE == 0) {
            int b = gq / Nq, p = gq - b * Nq;
            outb[((long)b * 64 + col) * 4096 + p] = val;   // transposed (b, col, p)
        } else {
            outb[(long)gq * 64 + col] = val;
        }
    }
}

// ---------------------------------------------------------------- transpose (B,R,C) -> (B,C,R)
__global__ void k_transp(const float* __restrict__ src, float* __restrict__ dst, int R, int C) {
    __shared__ float t[32][33];
    int b = blockIdx.z;
    int c0 = blockIdx.x * 32, r0 = blockIdx.y * 32;
    int tx = threadIdx.x, ty0 = threadIdx.y;    // (32,8)
    for (int yy = ty0; yy < 32; yy += 8) {
        int r = r0 + yy, c = c0 + tx;
        if (r < R && c < C) t[yy][tx] = src[((long)b * R + r) * C + c];
    }
    __syncthreads();
    for (int yy = ty0; yy < 32; yy += 8) {
        int c = c0 + yy, r = r0 + tx;
        if (r < R && c < C) dst[((long)b * C + c) * R + r] = t[tx][yy];
    }
}

// ---------------------------------------------------------------- FNO: truncated forward DFT
__global__ void __launch_bounds__(1024) k_f1(const float* __restrict__ x, float* __restrict__ Xh) {
    int blk = blockIdx.x;    // b*64 + ch
    int tid = threadIdx.x;   // 1024
    __shared__ __align__(16) float img[4096];
    __shared__ float Tre[64][12], Tim[64][12];
    __shared__ float cs[64], sn[64];
    if (tid < 64) {
        double a = (2.0 * PI_ / 64.0) * (double)tid;
        cs[tid] = (float)cos(a);
        sn[tid] = (float)sin(a);
    }
    ((float4*)img)[tid] = ((const float4*)(x + (long)blk * 4096))[tid];
    __syncthreads();
    if (tid < 768) {                             // (h, c)
        int h = tid / 12, c = tid - 12 * h;
        float re = 0.f, im = 0.f;
        for (int w = 0; w < 64; w++) {
            float v = img[h * 64 + w];
            int k = (c * w) & 63;
            re = fmaf(v, cs[k], re);
            im = fmaf(-v, sn[k], im);
        }
        Tre[h][c] = re; Tim[h][c] = im;
    }
    __syncthreads();
    if (tid < 288) {                             // (x24, c12)
        int xx = tid / 12, c = tid - 12 * xx;
        int r = (xx < 12) ? xx : (xx + 40);
        float re = 0.f, im = 0.f;
        for (int h = 0; h < 64; h++) {
            int k = (r * h) & 63;
            float cr = cs[k], si = sn[k];
            float a = Tre[h][c], bb = Tim[h][c];
            re += a * cr + bb * si;
            im += bb * cr - a * si;
        }
        Xh[((long)blk * 288 + tid) * 2] = re;
        Xh[((long)blk * 288 + tid) * 2 + 1] = im;
    }
}

// mode-mix: Yhat[b,o,m] = sum_i Wc[i,o,m] * Xhat[b,i,m]
__global__ void __launch_bounds__(256) k_f2(const float* __restrict__ Xh, const float* __restrict__ s1,
                                            const float* __restrict__ s2, float* __restrict__ Yh) {
    int m = blockIdx.x;                  // 0..287
    int xx = m / 12, y = m - 12 * xx;
    const float* W; int xw;
    if (xx < 12) { W = s1; xw = xx; } else { W = s2; xw = xx - 12; }
    __shared__ float xr[128], xi[128];
    __shared__ float pr[256], pi[256];
    int tid = threadIdx.x;               // 256
    if (tid < 128) {
        int bb = tid >> 6, i = tid & 63;
        xr[tid] = Xh[(((long)bb * 64 + i) * 288 + m) * 2];
        xi[tid] = Xh[(((long)bb * 64 + i) * 288 + m) * 2 + 1];
    }
    __syncthreads();
    int half = tid >> 7;
    int t2 = tid & 127;
    int bb = t2 >> 6, o = t2 & 63;
    float re = 0.f, im = 0.f;
    for (int i = half * 32; i < half * 32 + 32; i++) {
        long wb = (long)i * 18432 + (long)o * 288 + xw * 24 + y * 2;
        float wr = W[wb], wi = W[wb + 1];
        float a = xr[bb * 64 + i], cc = xi[bb * 64 + i];
        re += a * wr - cc * wi;
        im += a * wi + cc * wr;
    }
    pr[tid] = re; pi[tid] = im;
    __syncthreads();
    if (tid < 128) {
        float re2 = pr[tid] + pr[tid + 128];
        float im2 = pi[tid] + pi[tid + 128];
        Yh[(((long)bb * 64 + o) * 288 + m) * 2] = re2;
        Yh[(((long)bb * 64 + o) * 288 + m) * 2 + 1] = im2;
    }
}

// inverse DFT + pointwise conv + bias + InstanceNorm + GELU, fused per (b, out-channel)
__global__ void __launch_bounds__(1024) k_f3(const float* __restrict__ Yh, const float* __restrict__ x,
                                             const float* __restrict__ pwW, const float* __restrict__ pwb,
                                             float* __restrict__ xo) {
    int blk = blockIdx.x;
    int b = blk >> 6, o = blk & 63;
    int tid = threadIdx.x;   // 1024; each thread owns 4 consecutive pixels
    __shared__ float yre[288], yim[288];
    __shared__ float Qre[64][12], Qim[64][12];
    __shared__ float cs[64], sn[64];
    __shared__ float red[1024];
    if (tid < 64) {
        double a = (2.0 * PI_ / 64.0) * (double)tid;
        cs[tid] = (float)cos(a);
        sn[tid] = (float)sin(a);
    }
    if (tid < 288) {
        yre[tid] = Yh[((long)blk * 288 + tid) * 2];
        yim[tid] = Yh[((long)blk * 288 + tid) * 2 + 1];
    }
    __syncthreads();
    if (tid < 768) {    // (h, c): complex ifft along rows (1/64 scale)
        int h = tid / 12, c = tid - 12 * h;
        float re = 0.f, im = 0.f;
#pragma unroll
        for (int xx = 0; xx < 24; xx++) {
            int r = (xx < 12) ? xx : (xx + 40);
            int k = (r * h) & 63;
            float wr = cs[k], wi = sn[k];
            float a = yre[xx * 12 + c], bb = yim[xx * 12 + c];
            re += a * wr - bb * wi;
            im += a * wi + bb * wr;
        }
        Qre[h][c] = re * (1.0f / 64.0f);
        Qim[h][c] = im * (1.0f / 64.0f);
    }
    __syncthreads();
    float bias = pwb[o];
    int h = tid >> 4;
    int w0 = (tid & 15) * 4;
    float sp0, sp1, sp2, sp3;
    {
        float base = Qre[h][0];
        sp0 = sp1 = sp2 = sp3 = base;
#pragma unroll
        for (int c = 1; c < 12; c++) {
            float qr = Qre[h][c], qi = Qim[h][c];
            int k0 = (c * w0) & 63, k1 = (c * (w0 + 1)) & 63;
            int k2 = (c * (w0 + 2)) & 63, k3 = (c * (w0 + 3)) & 63;
            sp0 += 2.0f * (qr * cs[k0] - qi * sn[k0]);
            sp1 += 2.0f * (qr * cs[k1] - qi * sn[k1]);
            sp2 += 2.0f * (qr * cs[k2] - qi * sn[k2]);
            sp3 += 2.0f * (qr * cs[k3] - qi * sn[k3]);
        }
    }
    float a0 = sp0 * (1.0f / 64.0f) + bias;
    float a1 = sp1 * (1.0f / 64.0f) + bias;
    float a2 = sp2 * (1.0f / 64.0f) + bias;
    float a3 = sp3 * (1.0f / 64.0f) + bias;
    const float* xb = x + ((long)b * 64) * 4096 + tid * 4;
    for (int i = 0; i < 64; i++) {
        float wv = pwW[o * 64 + i];
        const float4 xv = *(const float4*)(xb + (long)i * 4096);
        a0 = fmaf(xv.x, wv, a0);
        a1 = fmaf(xv.y, wv, a1);
        a2 = fmaf(xv.z, wv, a2);
        a3 = fmaf(xv.w, wv, a3);
    }
    red[tid] = a0 + a1 + a2 + a3;
    __syncthreads();
    for (int d = 512; d > 0; d >>= 1) { if (tid < d) red[tid] += red[tid + d]; __syncthreads(); }
    float mu = red[0] * (1.0f / 4096.0f);
    __syncthreads();
    float d0 = a0 - mu, d1 = a1 - mu, d2 = a2 - mu, d3 = a3 - mu;
    red[tid] = d0 * d0 + d1 * d1 + d2 * d2 + d3 * d3;
    __syncthreads();
    for (int d = 512; d > 0; d >>= 1) { if (tid < d) red[tid] += red[tid + d]; __syncthreads(); }
    float var = red[0] * (1.0f / 4096.0f);
    float inv = 1.0f / sqrtf(var + 1e-5f);
    float4 ov = make_float4(gelu_f(d0 * inv), gelu_f(d1 * inv), gelu_f(d2 * inv), gelu_f(d3 * inv));
    *(float4*)&xo[(long)blk * 4096 + tid * 4] = ov;
}

// ---------------------------------------------------------------- projection MLP (64 -> 64 -> 3)
__global__ void __launch_bounds__(256) k_proj(
    const float* __restrict__ y, const float* __restrict__ W1, const float* __restrict__ b1,
    const float* __restrict__ W2, const float* __restrict__ b2, float* __restrict__ out) {
    __shared__ __align__(16) float yr[4][64];
    __shared__ float h[4][64];
    int ql = threadIdx.x >> 6, j = threadIdx.x & 63;
    long node = (long)blockIdx.x * 4 + ql;
    yr[ql][j] = y[node * 64 + j];
    __syncthreads();
    float a = b1[j];
    for (int k = 0; k < 64; k += 4) {
        float w0 = W1[(k + 0) * 64 + j], w1 = W1[(k + 1) * 64 + j];
        float w2 = W1[(k + 2) * 64 + j], w3 = W1[(k + 3) * 64 + j];
        const float4 hv = *(const float4*)&yr[ql][k];
        a = fmaf(hv.x, w0, fmaf(hv.y, w1, fmaf(hv.z, w2, fmaf(hv.w, w3, a))));
    }
    h[ql][j] = gelu_f(a);
    __syncthreads();
    if (j < 3) {
        float a2 = b2[j];
        for (int k = 0; k < 64; k++) a2 = fmaf(h[ql][k], W2[k * 3 + j], a2);
        out[node * 3 + j] = a2;
    }
}

// ---------------------------------------------------------------- launch
extern "C" void kernel_launch(void* const* d_in, const int* in_sizes, int n_in,
                              void* d_out, int out_size, void* d_ws, size_t ws_size,
                              hipStream_t stream) {
    (void)in_sizes; (void)n_in; (void)out_size; (void)ws_size;
    const float* coords   = (const float*)d_in[0];
    const float* features = (const float*)d_in[1];
    const float* lift_W1 = (const float*)d_in[2];
    const float* lift_b1 = (const float*)d_in[3];
    const float* lift_W2 = (const float*)d_in[4];
    const float* lift_b2 = (const float*)d_in[5];
    const float* gin_W1 = (const float*)d_in[6];
    const float* gin_b1 = (const float*)d_in[7];
    const float* gin_W2 = (const float*)d_in[8];
    const float* gin_b2 = (const float*)d_in[9];
    const float* gin_W3 = (const float*)d_in[10];
    const float* gin_b3 = (const float*)d_in[11];
    const float* spec1 = (const float*)d_in[12];
    const float* spec2 = (const float*)d_in[13];
    const float* pw_W  = (const float*)d_in[14];
    const float* pw_b  = (const float*)d_in[15];
    const float* gout_W1 = (const float*)d_in[16];
    const float* gout_b1 = (const float*)d_in[17];
    const float* gout_W2 = (const float*)d_in[18];
    const float* gout_b2 = (const float*)d_in[19];
    const float* gout_W3 = (const float*)d_in[20];
    const float* gout_b3 = (const float*)d_in[21];
    const float* proj_W1 = (const float*)d_in[22];
    const float* proj_b1 = (const float*)d_in[23];
    const float* proj_W2 = (const float*)d_in[24];
    const float* proj_b2 = (const float*)d_in[25];

    char* ws = (char*)d_ws;
    size_t off = 0;
    auto alloc = [&](size_t bytes) -> char* {
        char* p = ws + off;
        off = (off + bytes + 255) & ~(size_t)255;
        return p;
    };
    float4* grid_pack = (float4*)alloc((size_t)NG * 16);
    float*  feat      = (float*)alloc((size_t)B_ * N_ * 64 * 4);
    int*    bin_cnt   = (int*)alloc((size_t)B_ * 4096 * 4);
    int*    bin_fill  = (int*)alloc((size_t)B_ * 4096 * 4);
    int*    bin_off   = (int*)alloc((size_t)B_ * 4097 * 4);
    float4* srt       = (float4*)alloc((size_t)B_ * N_ * 16);
    int*    idx_in    = (int*)alloc((size_t)B_ * NG * 16 * 4);
    float*  dist_in   = (float*)alloc((size_t)B_ * NG * 16 * 4);
    float*  lastd_in  = (float*)alloc((size_t)B_ * NG * 4);
    float*  sig_in    = (float*)alloc(256);
    float*  xb0       = (float*)alloc((size_t)B_ * 64 * NG * 4);
    float*  xb1       = (float*)alloc((size_t)B_ * 64 * NG * 4);
    float*  Xh        = (float*)alloc((size_t)B_ * 64 * 288 * 2 * 4);
    float*  Yh        = (float*)alloc((size_t)B_ * 64 * 288 * 2 * 4);
    float*  g2        = (float*)alloc((size_t)B_ * NG * 64 * 4);
    int*    idx_out   = (int*)alloc((size_t)B_ * N_ * 16 * 4);
    float*  dist_out  = (float*)alloc((size_t)B_ * N_ * 16 * 4);
    float*  lastd_out = (float*)alloc((size_t)B_ * N_ * 4);
    float*  sig_out   = (float*)alloc(256);
    float*  ybuf      = (float*)alloc((size_t)B_ * N_ * 64 * 4);

    hipMemsetAsync(bin_cnt, 0, (size_t)B_ * 4096 * 4, stream);
    hipMemsetAsync(bin_fill, 0, (size_t)B_ * 4096 * 4, stream);

    k_lift<<<(B_ * N_) / 4, 256, 0, stream>>>(features, lift_W1, lift_b1, lift_W2, lift_b2, feat);
    k_bincount<<<(B_ * N_) / 256, 256, 0, stream>>>((const float2*)coords, bin_cnt, grid_pack);
    k_binscan<<<B_, 1024, 0, stream>>>(bin_cnt, bin_off);
    k_binscatter<<<(B_ * N_) / 256, 256, 0, stream>>>((const float2*)coords, bin_off, bin_fill, srt);
    k_knn_in<<<(B_ * NG * 64) / 256, 256, 0, stream>>>(grid_pack, srt, bin_off, idx_in, dist_in, lastd_in);
    k_median_bis<<<1, 1024, 0, stream>>>(lastd_in, B_ * NG, sig_in);
    k_edge<0><<<(B_ * NG) / 8, 256, 0, stream>>>(idx_in, dist_in, sig_in,
        (const float2*)coords, grid_pack, feat,
        gin_W1, gin_b1, gin_W2, gin_b2, gin_W3, gin_b3, xb0, NG, N_);
    float* xc = xb0; float* xn = xb1;
    for (int d = 0; d < 3; d++) {
        k_f1<<<B_ * 64, 1024, 0, stream>>>(xc, Xh);
        k_f2<<<288, 256, 0, stream>>>(Xh, spec1 + (size_t)d * 1179648, spec2 + (size_t)d * 1179648, Yh);
        k_f3<<<B_ * 64, 1024, 0, stream>>>(Yh, xc, pw_W + (size_t)d * 4096, pw_b + (size_t)d * 64, xn);
        float* tmp = xc; xc = xn; xn = tmp;
    }
    {
        dim3 g(NG / 32, 64 / 32, B_); dim3 t(32, 8);
        k_transp<<<g, t, 0, stream>>>(xc, g2, 64, NG);
    }
    k_knn_out<<<(B_ * N_ * 64) / 256, 256, 0, stream>>>((const float2*)coords, grid_pack, idx_out, dist_out, lastd_out);
    k_median_bis<<<1, 1024, 0, stream>>>(lastd_out, B_ * N_, sig_out);
    k_edge<1><<<(B_ * N_) / 8, 256, 0, stream>>>(idx_out, dist_out, sig_out,
        (const float2*)coords, grid_pack, g2,
        gout_W1, gout_b1, gout_W2, gout_b2, gout_W3, gout_b3, ybuf, N_, NG);
    k_proj<<<(B_ * N_) / 4, 256, 0, stream>>>(ybuf, proj_W1, proj_b1, proj_W2, proj_b2, (float*)d_out);
}